// Round 7
// baseline (612.556 us; speedup 1.0000x reference)
//
#include <hip/hip_runtime.h>

typedef __attribute__((ext_vector_type(8))) short bf16x8;
typedef __attribute__((ext_vector_type(8))) unsigned short u16x8;
typedef __attribute__((ext_vector_type(4))) float f32x4;
typedef __attribute__((ext_vector_type(2))) unsigned uint2v;
typedef __attribute__((ext_vector_type(4))) unsigned uint4v;

#define DEVINL __device__ __forceinline__

constexpr int TB = 2;        // batch
constexpr int TT = 4096;     // seq len
constexpr int TD = 512;      // model dim
constexpr int TH = 8;        // heads
constexpr int THD = 64;      // head dim
constexpr int TM = TB * TT;  // 8192 flattened rows

// fp32 -> bf16 round-to-nearest-even
DEVINL unsigned short f2b(float f) {
  unsigned u = __builtin_bit_cast(unsigned, f);
  u += 0x7FFFu + ((u >> 16) & 1u);
  return (unsigned short)(u >> 16);
}

// pack 2 f32 -> 2 bf16 in one dword (lo -> low16, hi -> high16), RNE
DEVINL unsigned cvtpk(float lo, float hi) {
  unsigned r;
  asm("v_cvt_pk_bf16_f32 %0, %1, %2" : "=v"(r) : "v"(lo), "v"(hi));
  return r;
}

// ---------------------------------------------------------------------------
// GEMM: Y = X[M][512] @ W[512][512]^T  (torch Linear).
// MODE 0: bf16 row-major. MODE 1: fp32 + bias. MODE 2: bf16 per-head
// transposed VT[b][h][d][T] via swapped mfma operands.   (unchanged from r6)
// ---------------------------------------------------------------------------
template<int MODE>
__global__ __launch_bounds__(256, 2)
void gemm_xwt(const float* __restrict__ X, const float* __restrict__ W,
              unsigned short* __restrict__ Yb, float* __restrict__ Yf,
              const float* __restrict__ bias)
{
  constexpr int K = TD, N = TD;
  __shared__ unsigned short As[128][72];
  __shared__ unsigned short Bs[128][72];

  const int t    = threadIdx.x;
  const int lane = t & 63, w = t >> 6;
  const int fr = lane & 15, fq = lane >> 4;
  const int wr = (w >> 1) * 64, wc = (w & 1) * 64;
  const int bm = blockIdx.x * 128, bn = blockIdx.y * 128;
  const int srow = t >> 1;
  const int skh  = (t & 1) * 32;

  f32x4 acc[4][4];
  #pragma unroll
  for (int i = 0; i < 4; ++i)
    #pragma unroll
    for (int j = 0; j < 4; ++j)
      acc[i][j] = f32x4{0.f, 0.f, 0.f, 0.f};

  for (int k0 = 0; k0 < K; k0 += 64) {
    const float* srcA = X + (size_t)(bm + srow) * K + k0 + skh;
    const float* srcB = W + (size_t)(bn + srow) * K + k0 + skh;
    #pragma unroll
    for (int i = 0; i < 4; ++i) {
      float4 a0 = ((const float4*)srcA)[2 * i];
      float4 a1 = ((const float4*)srcA)[2 * i + 1];
      u16x8 oa = {f2b(a0.x), f2b(a0.y), f2b(a0.z), f2b(a0.w),
                  f2b(a1.x), f2b(a1.y), f2b(a1.z), f2b(a1.w)};
      *(u16x8*)&As[srow][skh + i * 8] = oa;
      float4 b0 = ((const float4*)srcB)[2 * i];
      float4 b1 = ((const float4*)srcB)[2 * i + 1];
      u16x8 ob = {f2b(b0.x), f2b(b0.y), f2b(b0.z), f2b(b0.w),
                  f2b(b1.x), f2b(b1.y), f2b(b1.z), f2b(b1.w)};
      *(u16x8*)&Bs[srow][skh + i * 8] = ob;
    }
    __syncthreads();
    #pragma unroll
    for (int kk = 0; kk < 2; ++kk) {
      bf16x8 af[4], bfv[4];
      #pragma unroll
      for (int i = 0; i < 4; ++i)
        af[i] = *(const bf16x8*)&As[wr + i * 16 + fr][kk * 32 + fq * 8];
      #pragma unroll
      for (int j = 0; j < 4; ++j)
        bfv[j] = *(const bf16x8*)&Bs[wc + j * 16 + fr][kk * 32 + fq * 8];
      #pragma unroll
      for (int i = 0; i < 4; ++i)
        #pragma unroll
        for (int j = 0; j < 4; ++j) {
          if (MODE == 2)
            acc[i][j] = __builtin_amdgcn_mfma_f32_16x16x32_bf16(bfv[i], af[j], acc[i][j], 0, 0, 0);
          else
            acc[i][j] = __builtin_amdgcn_mfma_f32_16x16x32_bf16(af[i], bfv[j], acc[i][j], 0, 0, 0);
        }
    }
    __syncthreads();
  }

  #pragma unroll
  for (int i = 0; i < 4; ++i) {
    #pragma unroll
    for (int j = 0; j < 4; ++j) {
      #pragma unroll
      for (int ii = 0; ii < 4; ++ii) {
        float v = acc[i][j][ii];
        if (MODE == 2) {
          const int Nidx = bn + wc + i * 16 + fq * 4 + ii;
          const int Midx = bm + wr + j * 16 + fr;
          const int h = Nidx >> 6, d = Nidx & (THD - 1);
          const int b = Midx >> 12, tt = Midx & (TT - 1);
          Yb[((size_t)(b * TH + h) * THD + d) * TT + tt] = f2b(v);
        } else {
          const int gm = bm + wr + i * 16 + fq * 4 + ii;
          const int gn = bn + wc + j * 16 + fr;
          if (MODE == 1) Yf[(size_t)gm * N + gn] = v + bias[gn];
          else           Yb[(size_t)gm * N + gn] = f2b(v);
        }
      }
    }
  }
}

// ---------------------------------------------------------------------------
// Fused attention, BARRIER-FREE main loops. Block = (b,h,q-block of 64),
// 4 waves. Wave w owns the CONTIGUOUS kv range [w*1024, (w+1)*1024), walked
// in 16-kv chunks. K/V fragments are loaded directly from global (L2/L3-
// resident; LDS staging saves no traffic in the kv-split form and costs
// barriers). Swapped QK (mfma(K,Q)): per lane q = qf*16+fr (lane-local),
// kv = chunk + fq*4 + i -> f32x4 NT store is 16B contiguous along kv, and
// per row each wave's writes advance sequentially through its 4KB quarter
// (DRAM-page friendly). cvt_pk'd P is directly the PV A-fragment; PV per
// chunk-pair (k=32) with the same custom k-order on P and V.
// Waves sync only twice: lsum cross-wave reduce and final Z reduce.
// ---------------------------------------------------------------------------
__global__ __launch_bounds__(256, 2)
void attn_fused(const unsigned short* __restrict__ Qb,
                const unsigned short* __restrict__ Kb,
                const unsigned short* __restrict__ VTg,
                float* __restrict__ attnO, float* __restrict__ Z)
{
  __shared__ float Lred[4][4][16];   // [w][qf][fr]
  __shared__ float Zs[64][68];       // cross-wave Z reduce

  const int t    = threadIdx.x;
  const int lane = t & 63, w = t >> 6;        // w = 0..3 (kv quarter owner)
  const int fr = lane & 15, fq = lane >> 4;
  const int bh = blockIdx.y;                  // b*8+h
  const int b  = bh >> 3, h = bh & 7;
  const int q0 = blockIdx.x * 64;

  const size_t rowKV  = ((size_t)(b * TT)) * TD + h * THD;
  const size_t vtBase = (size_t)bh * THD * TT;

  // Q B-frags for the 4 q-groups (q = qf*16 + fr), held all kernel
  bf16x8 aq[4][2];
  #pragma unroll
  for (int qf = 0; qf < 4; ++qf) {
    const unsigned short* qsrc =
        Qb + ((size_t)(b * TT + q0 + qf * 16 + fr)) * TD + h * THD;
    aq[qf][0] = *(const bf16x8*)(qsrc + fq * 8);
    aq[qf][1] = *(const bf16x8*)(qsrc + 32 + fq * 8);
  }

  constexpr float K2 = 0.18033688011112042f;   // (1/8) * log2(e)

  // per-lane K fragment base: row (kv + fr), d-offset fq*8 (+32 for half 2)
  const unsigned short* kbase = Kb + rowKV + (size_t)fr * TD + fq * 8;
  const int kvw = w * 1024;                    // wave's kv range base
  constexpr size_t CSTR = (size_t)16 * TD;     // 16 kv rows

  // ---- pass 1: denominators over this wave's kv range (no barriers) ----
  float lsum[4] = {0.f, 0.f, 0.f, 0.f};
  {
    const unsigned short* kp = kbase + (size_t)kvw * TD;
    u16x8 kn0 = *(const u16x8*)kp;
    u16x8 kn1 = *(const u16x8*)(kp + 32);
    for (int c = 0; c < 64; ++c) {
      bf16x8 ak0 = __builtin_bit_cast(bf16x8, kn0);
      bf16x8 ak1 = __builtin_bit_cast(bf16x8, kn1);
      if (c + 1 < 64) {
        const unsigned short* np = kp + (size_t)(c + 1) * CSTR;
        kn0 = *(const u16x8*)np;
        kn1 = *(const u16x8*)(np + 32);
      }
      #pragma unroll
      for (int qf = 0; qf < 4; ++qf) {
        f32x4 s = f32x4{0.f, 0.f, 0.f, 0.f};
        s = __builtin_amdgcn_mfma_f32_16x16x32_bf16(ak0, aq[qf][0], s, 0, 0, 0);
        s = __builtin_amdgcn_mfma_f32_16x16x32_bf16(ak1, aq[qf][1], s, 0, 0, 0);
        lsum[qf] += __builtin_amdgcn_exp2f(s[0] * K2) +
                    __builtin_amdgcn_exp2f(s[1] * K2) +
                    __builtin_amdgcn_exp2f(s[2] * K2) +
                    __builtin_amdgcn_exp2f(s[3] * K2);
      }
    }
  }
  // reduce over fq (kv sub-slots), then across waves via LDS
  #pragma unroll
  for (int qf = 0; qf < 4; ++qf) {
    lsum[qf] += __shfl_xor(lsum[qf], 16, 64);
    lsum[qf] += __shfl_xor(lsum[qf], 32, 64);
  }
  if (fq == 0) {
    #pragma unroll
    for (int qf = 0; qf < 4; ++qf) Lred[w][qf][fr] = lsum[qf];
  }
  __syncthreads();
  float l2i[4];
  #pragma unroll
  for (int qf = 0; qf < 4; ++qf) {
    float s = Lred[0][qf][fr] + Lred[1][qf][fr] +
              Lred[2][qf][fr] + Lred[3][qf][fr];
    l2i[qf] = -__log2f(s);
  }

  // ---- pass 2: recompute, NT-store attn, accumulate PV (no barriers) ----
  f32x4 accz[4][4];     // [qf][df] partial Z over this wave's kv range
  #pragma unroll
  for (int i = 0; i < 4; ++i)
    #pragma unroll
    for (int j = 0; j < 4; ++j)
      accz[i][j] = f32x4{0.f, 0.f, 0.f, 0.f};

  // attn base for this lane: row q0+qf*16+fr (qf adds 16*TT), col kv + fq*4
  float* abase = attnO + ((size_t)bh * TT + q0 + fr) * TT + fq * 4;
  // V fragment base: row d = df*16+fr (df adds 16*TT), col kv + fq*4
  const unsigned short* vbase = VTg + vtBase + (size_t)fr * TT + fq * 4;

  for (int pr = 0; pr < 32; ++pr) {
    const int kvb0 = kvw + pr * 32;          // chunk pair: kvb0, kvb0+16
    // K fragments for both chunks (issued first)
    const unsigned short* kp0 = kbase + (size_t)kvb0 * TD;
    const unsigned short* kp1 = kp0 + CSTR;
    u16x8 a00 = *(const u16x8*)kp0;
    u16x8 a01 = *(const u16x8*)(kp0 + 32);
    u16x8 a10 = *(const u16x8*)kp1;
    u16x8 a11 = *(const u16x8*)(kp1 + 32);
    // V fragments for the pair
    uint2v vlo[4], vhi[4];
    #pragma unroll
    for (int df = 0; df < 4; ++df) {
      const unsigned short* vp = vbase + (size_t)df * 16 * TT + kvb0;
      vlo[df] = *(const uint2v*)vp;
      vhi[df] = *(const uint2v*)(vp + 16);
    }

    unsigned pa[4][4];   // P as A-frag dwords [qf][half*2 + k]
    // chunk 0
    #pragma unroll
    for (int qf = 0; qf < 4; ++qf) {
      f32x4 s = f32x4{0.f, 0.f, 0.f, 0.f};
      s = __builtin_amdgcn_mfma_f32_16x16x32_bf16(__builtin_bit_cast(bf16x8, a00), aq[qf][0], s, 0, 0, 0);
      s = __builtin_amdgcn_mfma_f32_16x16x32_bf16(__builtin_bit_cast(bf16x8, a01), aq[qf][1], s, 0, 0, 0);
      float p0 = __builtin_amdgcn_exp2f(fmaf(s[0], K2, l2i[qf]));
      float p1 = __builtin_amdgcn_exp2f(fmaf(s[1], K2, l2i[qf]));
      float p2 = __builtin_amdgcn_exp2f(fmaf(s[2], K2, l2i[qf]));
      float p3 = __builtin_amdgcn_exp2f(fmaf(s[3], K2, l2i[qf]));
      f32x4 pv4 = {p0, p1, p2, p3};
      __builtin_nontemporal_store(pv4, (f32x4*)(abase + (size_t)qf * 16 * TT + kvb0));
      pa[qf][0] = cvtpk(p0, p1);
      pa[qf][1] = cvtpk(p2, p3);
    }
    // chunk 1
    #pragma unroll
    for (int qf = 0; qf < 4; ++qf) {
      f32x4 s = f32x4{0.f, 0.f, 0.f, 0.f};
      s = __builtin_amdgcn_mfma_f32_16x16x32_bf16(__builtin_bit_cast(bf16x8, a10), aq[qf][0], s, 0, 0, 0);
      s = __builtin_amdgcn_mfma_f32_16x16x32_bf16(__builtin_bit_cast(bf16x8, a11), aq[qf][1], s, 0, 0, 0);
      float p0 = __builtin_amdgcn_exp2f(fmaf(s[0], K2, l2i[qf]));
      float p1 = __builtin_amdgcn_exp2f(fmaf(s[1], K2, l2i[qf]));
      float p2 = __builtin_amdgcn_exp2f(fmaf(s[2], K2, l2i[qf]));
      float p3 = __builtin_amdgcn_exp2f(fmaf(s[3], K2, l2i[qf]));
      f32x4 pv4 = {p0, p1, p2, p3};
      __builtin_nontemporal_store(pv4, (f32x4*)(abase + (size_t)qf * 16 * TT + kvb0 + 16));
      pa[qf][2] = cvtpk(p0, p1);
      pa[qf][3] = cvtpk(p2, p3);
    }
    // PV over the pair. k-order: k = fq*8+e -> kv = kvb0 + (e>>2)*16 + fq*4
    // + (e&3), identical on P (A, dword order) and V (B, lo/hi 8B).
    #pragma unroll
    for (int df = 0; df < 4; ++df) {
      uint4v bvv = {vlo[df][0], vlo[df][1], vhi[df][0], vhi[df][1]};
      bf16x8 bv = __builtin_bit_cast(bf16x8, bvv);
      #pragma unroll
      for (int qf = 0; qf < 4; ++qf) {
        uint4v pav = {pa[qf][0], pa[qf][1], pa[qf][2], pa[qf][3]};
        accz[qf][df] = __builtin_amdgcn_mfma_f32_16x16x32_bf16(
            __builtin_bit_cast(bf16x8, pav), bv, accz[qf][df], 0, 0, 0);
      }
    }
  }

  // ---- cross-wave Z reduction ----
  for (int ww = 0; ww < 4; ++ww) {
    if (w == ww) {
      #pragma unroll
      for (int qf = 0; qf < 4; ++qf)
        #pragma unroll
        for (int df = 0; df < 4; ++df)
          #pragma unroll
          for (int i = 0; i < 4; ++i) {
            float* zp = &Zs[qf * 16 + fq * 4 + i][df * 16 + fr];
            float v = accz[qf][df][i];
            if (ww != 0) v += *zp;
            *zp = v;
          }
    }
    __syncthreads();
  }
  // Z in [B*T, D] layout (head transpose folded into addressing)
  {
    const int r = t >> 2, c4 = (t & 3) * 16;
    float* zdst = Z + (size_t)(b * TT + q0 + r) * TD + h * THD + c4;
    #pragma unroll
    for (int i = 0; i < 4; ++i)
      *(f32x4*)(zdst + i * 4) = *(const f32x4*)&Zs[r][c4 + i * 4];
  }
}

// ---------------------------------------------------------------------------
extern "C" void kernel_launch(void* const* d_in, const int* in_sizes, int n_in,
                              void* d_out, int out_size, void* d_ws, size_t ws_size,
                              hipStream_t stream) {
  const float* queries = (const float*)d_in[0];
  const float* keys    = (const float*)d_in[1];
  const float* values  = (const float*)d_in[2];
  const float* Wq = (const float*)d_in[3];
  const float* Wk = (const float*)d_in[4];
  const float* Wv = (const float*)d_in[5];
  const float* Wo = (const float*)d_in[6];
  const float* bo = (const float*)d_in[7];

  float* out  = (float*)d_out;                       // [2,4096,512]
  float* attn = out + (size_t)TM * TD;               // [2,8,4096,4096]

  unsigned short* qb = (unsigned short*)d_ws;
  unsigned short* kb = qb + (size_t)TM * TD;
  unsigned short* vt = kb + (size_t)TM * TD;
  float*          zf = (float*)(vt + (size_t)TM * TD);

  dim3 gg(TM / 128, TD / 128), bb(256);
  gemm_xwt<0><<<gg, bb, 0, stream>>>(queries, Wq, qb, nullptr, nullptr);
  gemm_xwt<0><<<gg, bb, 0, stream>>>(keys,    Wk, kb, nullptr, nullptr);
  gemm_xwt<2><<<gg, bb, 0, stream>>>(values,  Wv, vt, nullptr, nullptr);

  attn_fused<<<dim3(TT / 64, TB * TH), bb, 0, stream>>>(qb, kb, vt, attn, zf);

  gemm_xwt<1><<<gg, bb, 0, stream>>>(zf, Wo, nullptr, out, bo);
}

// Round 8
// 531.270 us; speedup vs baseline: 1.1530x; 1.1530x over previous
//
#include <hip/hip_runtime.h>

typedef __attribute__((ext_vector_type(8))) short bf16x8;
typedef __attribute__((ext_vector_type(8))) unsigned short u16x8;
typedef __attribute__((ext_vector_type(4))) float f32x4;
typedef __attribute__((ext_vector_type(2))) unsigned uint2v;

#define DEVINL __device__ __forceinline__

constexpr int TB = 2;        // batch
constexpr int TT = 4096;     // seq len
constexpr int TD = 512;      // model dim
constexpr int TH = 8;        // heads
constexpr int THD = 64;      // head dim
constexpr int TM = TB * TT;  // 8192 flattened rows

// fp32 -> bf16 round-to-nearest-even
DEVINL unsigned short f2b(float f) {
  unsigned u = __builtin_bit_cast(unsigned, f);
  u += 0x7FFFu + ((u >> 16) & 1u);
  return (unsigned short)(u >> 16);
}

// pack 2 f32 -> 2 bf16 in one dword (lo -> low16, hi -> high16), RNE
DEVINL unsigned cvtpk(float lo, float hi) {
  unsigned r;
  asm("v_cvt_pk_bf16_f32 %0, %1, %2" : "=v"(r) : "v"(lo), "v"(hi));
  return r;
}

// barrier that only waits LDS ops (global stores may stay in flight)
DEVINL void lgkm_barrier() {
  asm volatile("s_waitcnt lgkmcnt(0)" ::: "memory");
  __builtin_amdgcn_s_barrier();
  __builtin_amdgcn_sched_barrier(0);
}

// ---------------------------------------------------------------------------
// GEMM: Y = X[M][512] @ W[512][512]^T  (torch Linear).
// MODE 0: bf16 row-major. MODE 1: fp32 + bias. MODE 2: bf16 per-head
// transposed VT[b][h][d][T] via swapped mfma operands.   (unchanged)
// ---------------------------------------------------------------------------
template<int MODE>
__global__ __launch_bounds__(256, 2)
void gemm_xwt(const float* __restrict__ X, const float* __restrict__ W,
              unsigned short* __restrict__ Yb, float* __restrict__ Yf,
              const float* __restrict__ bias)
{
  constexpr int K = TD, N = TD;
  __shared__ unsigned short As[128][72];
  __shared__ unsigned short Bs[128][72];

  const int t    = threadIdx.x;
  const int lane = t & 63, w = t >> 6;
  const int fr = lane & 15, fq = lane >> 4;
  const int wr = (w >> 1) * 64, wc = (w & 1) * 64;
  const int bm = blockIdx.x * 128, bn = blockIdx.y * 128;
  const int srow = t >> 1;
  const int skh  = (t & 1) * 32;

  f32x4 acc[4][4];
  #pragma unroll
  for (int i = 0; i < 4; ++i)
    #pragma unroll
    for (int j = 0; j < 4; ++j)
      acc[i][j] = f32x4{0.f, 0.f, 0.f, 0.f};

  for (int k0 = 0; k0 < K; k0 += 64) {
    const float* srcA = X + (size_t)(bm + srow) * K + k0 + skh;
    const float* srcB = W + (size_t)(bn + srow) * K + k0 + skh;
    #pragma unroll
    for (int i = 0; i < 4; ++i) {
      float4 a0 = ((const float4*)srcA)[2 * i];
      float4 a1 = ((const float4*)srcA)[2 * i + 1];
      u16x8 oa = {f2b(a0.x), f2b(a0.y), f2b(a0.z), f2b(a0.w),
                  f2b(a1.x), f2b(a1.y), f2b(a1.z), f2b(a1.w)};
      *(u16x8*)&As[srow][skh + i * 8] = oa;
      float4 b0 = ((const float4*)srcB)[2 * i];
      float4 b1 = ((const float4*)srcB)[2 * i + 1];
      u16x8 ob = {f2b(b0.x), f2b(b0.y), f2b(b0.z), f2b(b0.w),
                  f2b(b1.x), f2b(b1.y), f2b(b1.z), f2b(b1.w)};
      *(u16x8*)&Bs[srow][skh + i * 8] = ob;
    }
    __syncthreads();
    #pragma unroll
    for (int kk = 0; kk < 2; ++kk) {
      bf16x8 af[4], bfv[4];
      #pragma unroll
      for (int i = 0; i < 4; ++i)
        af[i] = *(const bf16x8*)&As[wr + i * 16 + fr][kk * 32 + fq * 8];
      #pragma unroll
      for (int j = 0; j < 4; ++j)
        bfv[j] = *(const bf16x8*)&Bs[wc + j * 16 + fr][kk * 32 + fq * 8];
      #pragma unroll
      for (int i = 0; i < 4; ++i)
        #pragma unroll
        for (int j = 0; j < 4; ++j) {
          if (MODE == 2)
            acc[i][j] = __builtin_amdgcn_mfma_f32_16x16x32_bf16(bfv[i], af[j], acc[i][j], 0, 0, 0);
          else
            acc[i][j] = __builtin_amdgcn_mfma_f32_16x16x32_bf16(af[i], bfv[j], acc[i][j], 0, 0, 0);
        }
    }
    __syncthreads();
  }

  #pragma unroll
  for (int i = 0; i < 4; ++i) {
    #pragma unroll
    for (int j = 0; j < 4; ++j) {
      #pragma unroll
      for (int ii = 0; ii < 4; ++ii) {
        float v = acc[i][j][ii];
        if (MODE == 2) {
          const int Nidx = bn + wc + i * 16 + fq * 4 + ii;
          const int Midx = bm + wr + j * 16 + fr;
          const int h = Nidx >> 6, d = Nidx & (THD - 1);
          const int b = Midx >> 12, tt = Midx & (TT - 1);
          Yb[((size_t)(b * TH + h) * THD + d) * TT + tt] = f2b(v);
        } else {
          const int gm = bm + wr + i * 16 + fq * 4 + ii;
          const int gn = bn + wc + j * 16 + fr;
          if (MODE == 1) Yf[(size_t)gm * N + gn] = v + bias[gn];
          else           Yb[(size_t)gm * N + gn] = f2b(v);
        }
      }
    }
  }
}

// ---------------------------------------------------------------------------
// Fused attention = r4 structure (q-split, swapped QK, lane-local P->PV via
// Ps LDS round-trip) with KV tile 32 and 4+ blocks/CU:
//   LDS 24 KB (Ks[2][32][72], VTs[2][64][40], Ps[4][16][40])
//   __launch_bounds__(256,4): VGPR cap 128 (per-thread state ~85 -> no spill)
// Whole grid (1024 blocks) resident in one round; 4+ waves/SIMD hide the
// per-tile chain (ds_read -> MFMA -> exp -> cvt -> PV -> barrier).
// ---------------------------------------------------------------------------
__global__ __launch_bounds__(256, 4)
void attn_fused(const unsigned short* __restrict__ Qb,
                const unsigned short* __restrict__ Kb,
                const unsigned short* __restrict__ VTg,
                float* __restrict__ attnO, float* __restrict__ Z)
{
  __shared__ unsigned short Ks[2][32][72];     // 9.0 KB  K rows [kv][d]
  __shared__ unsigned short VTs[2][64][40];    // 10.0 KB V^T rows [d][kv]
  __shared__ unsigned short Ps[4][16][40];     // 5.0 KB  per-wave P [q][kv]

  const int t    = threadIdx.x;
  const int lane = t & 63, w = t >> 6;         // w = 0..3 (q sixteenth)
  const int fr = lane & 15, fq = lane >> 4;
  const int bh = blockIdx.y;                   // b*8+h
  const int b  = bh >> 3, h = bh & 7;
  const int q0 = blockIdx.x * 64;

  const size_t rowKV  = ((size_t)(b * TT)) * TD + h * THD;
  const size_t vtBase = (size_t)bh * THD * TT;

  // K staging: 32 rows x 64 d; one 16B chunk per thread
  const int trK = t >> 3, tcK = (t & 7) * 8;
  // VT staging: 64 rows (d) x 32 kv; one 16B chunk per thread
  const int trV = t >> 2, tcV = (t & 3) * 8;

  auto loadK = [&](int kv0, u16x8& r) {
    r = *(const u16x8*)(Kb + rowKV + (size_t)(kv0 + trK) * TD + tcK);
  };
  auto loadVT = [&](int kv0, u16x8& r) {
    r = *(const u16x8*)(VTg + vtBase + (size_t)trV * TT + kv0 + tcV);
  };
  auto writeK  = [&](int buf, const u16x8& r) { *(u16x8*)&Ks[buf][trK][tcK]  = r; };
  auto writeVT = [&](int buf, const u16x8& r) { *(u16x8*)&VTs[buf][trV][tcV] = r; };

  // Q held in registers (B-operand of swapped QK; row = q = w*16+fr)
  const unsigned short* qsrc = Qb + ((size_t)(b * TT + q0 + w * 16 + fr)) * TD + h * THD;
  bf16x8 aq[2];
  aq[0] = *(const bf16x8*)(qsrc + fq * 8);
  aq[1] = *(const bf16x8*)(qsrc + 32 + fq * 8);

  constexpr int KVB = 32;
  constexpr int NT = TT / KVB;                 // 128 kv tiles
  constexpr float K2 = 0.18033688011112042f;   // (1/8) * log2(e)

  u16x8 kr, vr;
  loadK(0, kr);
  writeK(0, kr);
  lgkm_barrier();

  // ---- pass 1: row sums of exp(s/8) ----
  float lsum = 0.f;
  for (int j = 0; j < NT; ++j) {
    const int cur = j & 1;
    if (j + 1 < NT) loadK((j + 1) * KVB, kr);
    __builtin_amdgcn_s_setprio(1);
    #pragma unroll
    for (int n = 0; n < 2; ++n) {
      f32x4 s = f32x4{0.f, 0.f, 0.f, 0.f};
      #pragma unroll
      for (int kk = 0; kk < 2; ++kk) {
        bf16x8 ak = *(const bf16x8*)&Ks[cur][n * 16 + fr][kk * 32 + fq * 8];
        s = __builtin_amdgcn_mfma_f32_16x16x32_bf16(ak, aq[kk], s, 0, 0, 0);
      }
      #pragma unroll
      for (int i = 0; i < 4; ++i)
        lsum += __builtin_amdgcn_exp2f(s[i] * K2);
    }
    __builtin_amdgcn_s_setprio(0);
    if (j + 1 < NT) writeK(cur ^ 1, kr);
    lgkm_barrier();
  }
  // kv spread across fq groups; q is lane-local -> reduce over fq only
  lsum += __shfl_xor(lsum, 16, 64);
  lsum += __shfl_xor(lsum, 32, 64);
  const float l2i = -__log2f(lsum);    // log2(1/lsum)

  // ---- pass 2: recompute, write attn, accumulate PV ----
  loadK(0, kr);
  loadVT(0, vr);
  writeK(0, kr);
  writeVT(0, vr);
  lgkm_barrier();

  f32x4 accz[4];
  #pragma unroll
  for (int n = 0; n < 4; ++n) accz[n] = f32x4{0.f, 0.f, 0.f, 0.f};

  // attn row for this lane: q = q0 + w*16 + fr; within row: kv0 + n*16 + fq*4
  float* arow = attnO + ((size_t)bh * TT + q0 + w * 16 + fr) * TT + fq * 4;

  for (int j = 0; j < NT; ++j) {
    const int cur = j & 1;
    const int kv0 = j * KVB;
    if (j + 1 < NT) {
      loadK((j + 1) * KVB, kr);
      loadVT((j + 1) * KVB, vr);
    }
    // QK^T (swapped): s[n][i] = S[kv = kv0+n*16+fq*4+i][q = q0+w*16+fr]
    f32x4 sv[2];
    __builtin_amdgcn_s_setprio(1);
    #pragma unroll
    for (int n = 0; n < 2; ++n) {
      f32x4 s = f32x4{0.f, 0.f, 0.f, 0.f};
      #pragma unroll
      for (int kk = 0; kk < 2; ++kk) {
        bf16x8 ak = *(const bf16x8*)&Ks[cur][n * 16 + fr][kk * 32 + fq * 8];
        s = __builtin_amdgcn_mfma_f32_16x16x32_bf16(ak, aq[kk], s, 0, 0, 0);
      }
      sv[n] = s;
    }
    __builtin_amdgcn_s_setprio(0);
    // p = exp2(s*K2 + log2(1/lsum)); NT store; P -> Ps (bf16)
    #pragma unroll
    for (int n = 0; n < 2; ++n) {
      float p0 = __builtin_amdgcn_exp2f(fmaf(sv[n][0], K2, l2i));
      float p1 = __builtin_amdgcn_exp2f(fmaf(sv[n][1], K2, l2i));
      float p2 = __builtin_amdgcn_exp2f(fmaf(sv[n][2], K2, l2i));
      float p3 = __builtin_amdgcn_exp2f(fmaf(sv[n][3], K2, l2i));
      f32x4 pv4 = {p0, p1, p2, p3};
      __builtin_nontemporal_store(pv4, (f32x4*)(arow + kv0 + n * 16));
      uint2v u = {cvtpk(p0, p1), cvtpk(p2, p3)};
      *(uint2v*)&Ps[w][fr][n * 16 + fq * 4] = u;
    }
    // wave-local: Ps writes must land before reading P as A-fragments
    asm volatile("s_waitcnt lgkmcnt(0)" ::: "memory");
    __builtin_amdgcn_sched_barrier(0);
    __builtin_amdgcn_s_setprio(1);
    {
      bf16x8 ap = *(const bf16x8*)&Ps[w][fr][fq * 8];
      #pragma unroll
      for (int df = 0; df < 4; ++df) {
        bf16x8 bv = *(const bf16x8*)&VTs[cur][df * 16 + fr][fq * 8];
        accz[df] = __builtin_amdgcn_mfma_f32_16x16x32_bf16(ap, bv, accz[df], 0, 0, 0);
      }
    }
    __builtin_amdgcn_s_setprio(0);
    if (j + 1 < NT) {
      writeK(cur ^ 1, kr);
      writeVT(cur ^ 1, vr);
    }
    lgkm_barrier();
  }

  // Z in [B*T, D]; accz[df][i] = Z[q = q0+w*16+fq*4+i][d = df*16+fr]
  const size_t zbase = ((size_t)(b * TT + q0 + w * 16 + fq * 4)) * TD + h * THD + fr;
  #pragma unroll
  for (int df = 0; df < 4; ++df)
    #pragma unroll
    for (int i = 0; i < 4; ++i)
      Z[zbase + (size_t)i * TD + df * 16] = accz[df][i];
}

// ---------------------------------------------------------------------------
extern "C" void kernel_launch(void* const* d_in, const int* in_sizes, int n_in,
                              void* d_out, int out_size, void* d_ws, size_t ws_size,
                              hipStream_t stream) {
  const float* queries = (const float*)d_in[0];
  const float* keys    = (const float*)d_in[1];
  const float* values  = (const float*)d_in[2];
  const float* Wq = (const float*)d_in[3];
  const float* Wk = (const float*)d_in[4];
  const float* Wv = (const float*)d_in[5];
  const float* Wo = (const float*)d_in[6];
  const float* bo = (const float*)d_in[7];

  float* out  = (float*)d_out;                       // [2,4096,512]
  float* attn = out + (size_t)TM * TD;               // [2,8,4096,4096]

  unsigned short* qb = (unsigned short*)d_ws;
  unsigned short* kb = qb + (size_t)TM * TD;
  unsigned short* vt = kb + (size_t)TM * TD;
  float*          zf = (float*)(vt + (size_t)TM * TD);

  dim3 gg(TM / 128, TD / 128), bb(256);
  gemm_xwt<0><<<gg, bb, 0, stream>>>(queries, Wq, qb, nullptr, nullptr);
  gemm_xwt<0><<<gg, bb, 0, stream>>>(keys,    Wk, kb, nullptr, nullptr);
  gemm_xwt<2><<<gg, bb, 0, stream>>>(values,  Wv, vt, nullptr, nullptr);

  attn_fused<<<dim3(TT / 64, TB * TH), bb, 0, stream>>>(qb, kb, vt, attn, zf);

  gemm_xwt<1><<<gg, bb, 0, stream>>>(zf, Wo, nullptr, out, bo);
}